// Round 10
// baseline (653.609 us; speedup 1.0000x reference)
//
#include <hip/hip_runtime.h>
#include <math.h>

#define SQ 1024  // S
#define EE 512   // E
#define NB 4     // B
#define NH 8     // H

typedef __attribute__((ext_vector_type(8))) short bfrag;       // 8 bf16 (4 VGPRs)
typedef __attribute__((ext_vector_type(4))) float f32x4;       // MFMA C/D
typedef __attribute__((ext_vector_type(4))) unsigned short u16x4;
typedef __attribute__((ext_vector_type(8))) unsigned short u16x8;

typedef __attribute__((address_space(3))) unsigned int lds_u32;
typedef const __attribute__((address_space(1))) unsigned int glb_u32;

// Optimization barrier: forces materialization (rounding) so the compiler
// cannot FMA-contract or reassociate across numpy's op boundaries.
__device__ __forceinline__ float sep(float x) {
  asm volatile("" : "+v"(x));
  return x;
}

__device__ __forceinline__ unsigned short f2bf(float f) {
  unsigned u = __builtin_bit_cast(unsigned, f);
  unsigned r = (u + 0x7fffu + ((u >> 16) & 1u)) >> 16;
  return (unsigned short)r;
}
__device__ __forceinline__ float bf2f(unsigned short h) {
  unsigned u = ((unsigned)h) << 16;
  return __builtin_bit_cast(float, u);
}
__device__ __forceinline__ float bitf(unsigned u) { return __builtin_bit_cast(float, u); }

// packed f32x2 -> bf16x2 (lo16 = bf16(a), hi16 = bf16(b))
__device__ __forceinline__ unsigned cvtpk(float a, float b) {
  unsigned r;
  asm("v_cvt_pk_bf16_f32 %0, %1, %2" : "=v"(r) : "v"(a), "v"(b));
  return r;
}

__device__ __forceinline__ void split4(float4 v, u16x4& h, u16x4& l) {
  h.x = f2bf(v.x); l.x = f2bf(v.x - bf2f(h.x));
  h.y = f2bf(v.y); l.y = f2bf(v.y - bf2f(h.y));
  h.z = f2bf(v.z); l.z = f2bf(v.z - bf2f(h.z));
  h.w = f2bf(v.w); l.w = f2bf(v.w - bf2f(h.w));
}

// ================= LayerNorm, numpy-exact fp32 (np.mean pairwise) — FROZEN =================
__global__ __launch_bounds__(64) void ln_np(const float* __restrict__ x,
                                            const float* __restrict__ g,
                                            const float* __restrict__ b,
                                            float* __restrict__ y) {
  __shared__ float xs[EE];
  __shared__ float bc[2];
  long long t = blockIdx.x;
  int lane = threadIdx.x;
#pragma unroll
  for (int m = 0; m < 8; m++) xs[lane + 64 * m] = x[t * EE + lane + 64 * m];
  __syncthreads();
  int l = lane >> 3, a = lane & 7;
  float r = 0.f;
  if (lane < 32) {
    r = xs[l * 128 + a];
#pragma unroll
    for (int m = 1; m < 16; m++) r = r + xs[l * 128 + 8 * m + a];
  }
  r = r + __shfl_xor(r, 1);
  r = r + __shfl_xor(r, 2);
  r = r + __shfl_xor(r, 4);
  r = r + __shfl_xor(r, 8);
  r = r + __shfl_xor(r, 16);
  if (lane == 0) bc[0] = r / 512.0f;
  __syncthreads();
  float mean = bc[0];
  r = 0.f;
  if (lane < 32) {
#pragma unroll
    for (int m = 0; m < 16; m++) {
      float d = sep(xs[l * 128 + 8 * m + a] - mean);
      float s2 = sep(d * d);
      r = (m == 0) ? s2 : (r + s2);
    }
  }
  r = r + __shfl_xor(r, 1);
  r = r + __shfl_xor(r, 2);
  r = r + __shfl_xor(r, 4);
  r = r + __shfl_xor(r, 8);
  r = r + __shfl_xor(r, 16);
  if (lane == 0) bc[1] = r / 512.0f;
  __syncthreads();
  float var = bc[1];
  float rs = 1.0f / sqrtf(var + 1e-5f);
#pragma unroll
  for (int m = 0; m < 8; m++) {
    int i = lane + 64 * m;
    float d = sep(xs[i] - mean);
    float t1 = sep(d * rs);
    float t2 = sep(t1 * g[i]);
    y[t * EE + i] = t2 + b[i];
  }
}

// ===== LayerNorm (LN2) with split bf16 hi/lo output (same frozen math, split store) =====
__global__ __launch_bounds__(64) void ln_np_s(const float* __restrict__ x,
                                              const float* __restrict__ g,
                                              const float* __restrict__ b,
                                              unsigned short* __restrict__ yh,
                                              unsigned short* __restrict__ yl) {
  __shared__ float xs[EE];
  __shared__ float bc[2];
  long long t = blockIdx.x;
  int lane = threadIdx.x;
#pragma unroll
  for (int m = 0; m < 8; m++) xs[lane + 64 * m] = x[t * EE + lane + 64 * m];
  __syncthreads();
  int l = lane >> 3, a = lane & 7;
  float r = 0.f;
  if (lane < 32) {
    r = xs[l * 128 + a];
#pragma unroll
    for (int m = 1; m < 16; m++) r = r + xs[l * 128 + 8 * m + a];
  }
  r = r + __shfl_xor(r, 1);
  r = r + __shfl_xor(r, 2);
  r = r + __shfl_xor(r, 4);
  r = r + __shfl_xor(r, 8);
  r = r + __shfl_xor(r, 16);
  if (lane == 0) bc[0] = r / 512.0f;
  __syncthreads();
  float mean = bc[0];
  r = 0.f;
  if (lane < 32) {
#pragma unroll
    for (int m = 0; m < 16; m++) {
      float d = sep(xs[l * 128 + 8 * m + a] - mean);
      float s2 = sep(d * d);
      r = (m == 0) ? s2 : (r + s2);
    }
  }
  r = r + __shfl_xor(r, 1);
  r = r + __shfl_xor(r, 2);
  r = r + __shfl_xor(r, 4);
  r = r + __shfl_xor(r, 8);
  r = r + __shfl_xor(r, 16);
  if (lane == 0) bc[1] = r / 512.0f;
  __syncthreads();
  float var = bc[1];
  float rs = 1.0f / sqrtf(var + 1e-5f);
#pragma unroll
  for (int m = 0; m < 8; m++) {
    int i = lane + 64 * m;
    float d = sep(xs[i] - mean);
    float t1 = sep(d * rs);
    float t2 = sep(t1 * g[i]);
    float o = t2 + b[i];
    unsigned short hh = f2bf(o);
    yh[t * EE + i] = hh;
    yl[t * EE + i] = f2bf(o - bf2f(hh));
  }
}

// ================= distances — FROZEN math; also emits E = __expf(dist) for ctx gate =================
__global__ __launch_bounds__(256) void dist_np(const float* __restrict__ nq,
                                               const float* __restrict__ conv_w,
                                               const float* __restrict__ conv_b,
                                               float* __restrict__ dist,
                                               float* __restrict__ Edist) {
  int bh = blockIdx.x;
  int b = bh >> 3, h = bh & 7;
  float cb = conv_b[h];
  const float* W = conv_w + (long long)h * EE * 3;
  int s = blockIdx.y * 256 + threadIdx.x;
  float d = cb;
#pragma unroll
  for (int k = 0; k < 3; k++) {
    int t = s - 2 + k;
    if (t < 0) continue;
    const float* row = nq + ((long long)b * SQ + t) * EE;
    float acc = 0.f;
    for (int e = 0; e < EE; e++) acc = __builtin_fmaf(row[e], W[e * 3 + k], acc);
    d = sep(d + acc);
  }
  float dv = (float)tanh((double)d);
  dist[(long long)bh * SQ + s] = dv;
  Edist[(long long)bh * SQ + s] = __expf(dv);  // d in [-1,1]: no overflow; numerator-only use
}

__device__ __forceinline__ float gelu_exact(float x) {
  return 0.5f * x * (1.f + erff(x / 1.41421356237309504880f));
}

// ============ fp32 tiled NT-GEMM, 64x128 tile / 4x8 micro — FROZEN per-output chain ============
// Per-output accumulation chain is BIT-IDENTICAL to the original 64x64 gemm_nt:
// same k order (k0 step 16, kk 0..15), same `acc += a*b` statement, same
// SPLITK=384 boundary (two explicit loops), same sep() epilogue. Only the
// thread->output mapping and LDS geometry changed. Col groups {tx*4, 64+tx*4};
// 32+32 accumulator VGPRs (no spill), grid stays >=2 blocks/CU.
template <int ACT, int SPLITK>
__global__ __launch_bounds__(256) void gemm_nt3(const float* __restrict__ A, int lda, long long sA,
                                                const float* __restrict__ B, int ldb, long long sB,
                                                const float* __restrict__ bias,
                                                const float* __restrict__ Res,
                                                float* __restrict__ C, int ldc, long long sC,
                                                int K, float alpha) {
  __shared__ float As[16][68];
  __shared__ float Bs[16][132];
  int z = blockIdx.z;
  A += (long long)z * sA;
  B += (long long)z * sB;
  C += (long long)z * sC;
  if (Res) Res += (long long)z * sC;
  // XCD-aware block swizzle (nwg % 8 == 0 in our launches); pure locality.
  int gx = gridDim.x;
  int nwg = gx * (int)gridDim.y;
  int lin = blockIdx.y * gx + blockIdx.x;
  int cpx = nwg >> 3;
  int tl = (lin & 7) * cpx + (lin >> 3);
  int bx = tl % gx, by = tl / gx;
  int m0 = by * 64, n0 = bx * 128;
  int tid = threadIdx.x;
  int lr = tid >> 2, lc = tid & 3;
  int tx = tid & 15, ty = tid >> 4;
  float acc[4][8] = {};
  float acc2[4][8] = {};
  const float* Arow = A + (long long)(m0 + lr) * lda + lc * 4;
  const float* Brow0 = B + (long long)(n0 + lr) * ldb + lc * 4;
  const float* Brow1 = B + (long long)(n0 + 64 + lr) * ldb + lc * 4;
  float4 a4, b4[2];
  a4 = *(const float4*)(Arow);
  b4[0] = *(const float4*)(Brow0);
  b4[1] = *(const float4*)(Brow1);

  auto step = [&](int k0, float (*tgt)[8]) {
    __syncthreads();
    As[lc * 4 + 0][lr] = a4.x; As[lc * 4 + 1][lr] = a4.y;
    As[lc * 4 + 2][lr] = a4.z; As[lc * 4 + 3][lr] = a4.w;
    Bs[lc * 4 + 0][lr] = b4[0].x; Bs[lc * 4 + 1][lr] = b4[0].y;
    Bs[lc * 4 + 2][lr] = b4[0].z; Bs[lc * 4 + 3][lr] = b4[0].w;
    Bs[lc * 4 + 0][64 + lr] = b4[1].x; Bs[lc * 4 + 1][64 + lr] = b4[1].y;
    Bs[lc * 4 + 2][64 + lr] = b4[1].z; Bs[lc * 4 + 3][64 + lr] = b4[1].w;
    __syncthreads();
    int kn = (k0 + 16 < K) ? (k0 + 16) : k0;
    a4 = *(const float4*)(Arow + kn);
    b4[0] = *(const float4*)(Brow0 + kn);
    b4[1] = *(const float4*)(Brow1 + kn);
#pragma unroll
    for (int kk = 0; kk < 16; kk++) {
      float4 av = *(const float4*)&As[kk][ty * 4];
      float4 bv0 = *(const float4*)&Bs[kk][tx * 4];
      float4 bv1 = *(const float4*)&Bs[kk][64 + tx * 4];
      float a[4] = {av.x, av.y, av.z, av.w};
      float bb[8] = {bv0.x, bv0.y, bv0.z, bv0.w, bv1.x, bv1.y, bv1.z, bv1.w};
#pragma unroll
      for (int i = 0; i < 4; i++)
#pragma unroll
        for (int j = 0; j < 8; j++) tgt[i][j] += a[i] * bb[j];
    }
  };

  int k0 = 0;
  if (SPLITK > 0) {
    for (; k0 < SPLITK; k0 += 16) step(k0, acc);
    for (; k0 < K; k0 += 16) step(k0, acc2);
#pragma unroll
    for (int i = 0; i < 4; i++)
#pragma unroll
      for (int j = 0; j < 8; j++) acc[i][j] = sep(acc[i][j]) + acc2[i][j];
  } else {
    for (; k0 < K; k0 += 16) step(k0, acc);
  }

  float4 bias4a = make_float4(0.f, 0.f, 0.f, 0.f);
  float4 bias4b = make_float4(0.f, 0.f, 0.f, 0.f);
  if (ACT != 2 && bias) {
    bias4a = *(const float4*)(bias + n0 + tx * 4);
    bias4b = *(const float4*)(bias + n0 + 64 + tx * 4);
  }
#pragma unroll
  for (int i = 0; i < 4; i++) {
    int row = m0 + ty * 4 + i;
    float o[8];
    if (ACT == 2) {
#pragma unroll
      for (int j = 0; j < 8; j++) o[j] = acc[i][j] / alpha;
    } else {
      o[0] = sep(acc[i][0] * alpha) + bias4a.x;
      o[1] = sep(acc[i][1] * alpha) + bias4a.y;
      o[2] = sep(acc[i][2] * alpha) + bias4a.z;
      o[3] = sep(acc[i][3] * alpha) + bias4a.w;
      o[4] = sep(acc[i][4] * alpha) + bias4b.x;
      o[5] = sep(acc[i][5] * alpha) + bias4b.y;
      o[6] = sep(acc[i][6] * alpha) + bias4b.z;
      o[7] = sep(acc[i][7] * alpha) + bias4b.w;
    }
    if (ACT == 1) {
#pragma unroll
      for (int j = 0; j < 8; j++) o[j] = gelu_exact(o[j]);
    }
    if (Res) {
      float4 r4a = *(const float4*)(Res + (long long)row * ldc + n0 + tx * 4);
      float4 r4b = *(const float4*)(Res + (long long)row * ldc + n0 + 64 + tx * 4);
      o[0] = sep(o[0]) + r4a.x; o[1] = sep(o[1]) + r4a.y;
      o[2] = sep(o[2]) + r4a.z; o[3] = sep(o[3]) + r4a.w;
      o[4] = sep(o[4]) + r4b.x; o[5] = sep(o[5]) + r4b.y;
      o[6] = sep(o[6]) + r4b.z; o[7] = sep(o[7]) + r4b.w;
    }
    *(float4*)(C + (long long)row * ldc + n0 + tx * 4) = make_float4(o[0], o[1], o[2], o[3]);
    *(float4*)(C + (long long)row * ldc + n0 + 64 + tx * 4) = make_float4(o[4], o[5], o[6], o[7]);
  }
}

// ================= gated row sums: np.sum pairwise(1024) — FROZEN (fp64 exp) =================
__global__ __launch_bounds__(64) void rowsum_np(const float* __restrict__ scores,
                                                const float* __restrict__ dist,
                                                float* __restrict__ invrs) {
  __shared__ float wsm[SQ];
  int i = blockIdx.x;
  int z = blockIdx.y;
  int b = z >> 3;
  const float* srow = scores + ((long long)b * SQ + i) * SQ;
  const float* dz = dist + (long long)z * SQ;
  float di = dz[i];
  int lane = threadIdx.x;
#pragma unroll
  for (int m = 0; m < 16; m++) {
    int j = lane + 64 * m;
    float e = (float)exp((double)(dz[j] - di));
    float gg = 1.f / (1.f + e);
    wsm[j] = srow[j] * gg;
  }
  __syncthreads();
  int l = lane >> 3, a = lane & 7;
  float r = wsm[l * 128 + a];
#pragma unroll
  for (int m = 1; m < 16; m++) r = r + wsm[l * 128 + 8 * m + a];
  r = r + __shfl_xor(r, 1);
  r = r + __shfl_xor(r, 2);
  r = r + __shfl_xor(r, 4);
  r = r + __shfl_xor(r, 8);
  r = r + __shfl_xor(r, 16);
  r = r + __shfl_xor(r, 32);
  if (lane == 0) invrs[(long long)z * SQ + i] = 1.f / (r + 1e-12f);
}

// ================= V transpose + bf16 hi/lo split:  VhT/VlT[b][e][j] = split(V[b][j][e]) =================
__global__ __launch_bounds__(256) void vsplit_t(const float* __restrict__ qkv,
                                                unsigned short* __restrict__ VhT,
                                                unsigned short* __restrict__ VlT) {
  __shared__ float tile[64][65];
  int b = blockIdx.z;
  int j0 = blockIdx.x * 64;  // S tile
  int e0 = blockIdx.y * 64;  // E tile
  const float* V = qkv + (long long)b * SQ * (3 * EE) + 2 * EE;
  unsigned short* Vh = VhT + (long long)b * EE * SQ;
  unsigned short* Vl = VlT + (long long)b * EE * SQ;
  int tx = threadIdx.x & 15, ty = threadIdx.x >> 4;
#pragma unroll
  for (int r = 0; r < 4; r++) {
    int j = j0 + ty + r * 16;
    float4 v = *(const float4*)(V + (long long)j * (3 * EE) + e0 + tx * 4);
    tile[ty + r * 16][tx * 4 + 0] = v.x;
    tile[ty + r * 16][tx * 4 + 1] = v.y;
    tile[ty + r * 16][tx * 4 + 2] = v.z;
    tile[ty + r * 16][tx * 4 + 3] = v.w;
  }
  __syncthreads();
#pragma unroll
  for (int r = 0; r < 4; r++) {
    int el = ty + r * 16;
    float4 f;
    f.x = tile[tx * 4 + 0][el];
    f.y = tile[tx * 4 + 1][el];
    f.z = tile[tx * 4 + 2][el];
    f.w = tile[tx * 4 + 3][el];
    u16x4 hh, ll;
    split4(f, hh, ll);
    long long o = (long long)(e0 + el) * SQ + j0 + tx * 4;
    *(u16x4*)(Vh + o) = hh;
    *(u16x4*)(Vl + o) = ll;
  }
}

// ===== flat fp32 -> bf16 hi/lo split (weights); n4 = count/4 =====
__global__ __launch_bounds__(256) void wsplit(const float* __restrict__ W,
                                              unsigned short* __restrict__ Wh,
                                              unsigned short* __restrict__ Wl, int n4) {
  int i = blockIdx.x * 256 + threadIdx.x;
  if (i >= n4) return;
  float4 v = *(const float4*)(W + (long long)i * 4);
  u16x4 h, l;
  split4(v, h, l);
  *(u16x4*)(Wh + (long long)i * 4) = h;
  *(u16x4*)(Wl + (long long)i * 4) = l;
}

// ================= ctx GEMM via bf16x3 MFMA — r6 geometry + B-DMA + XOR LDS (r8, proven) ==========
__global__ __launch_bounds__(256, 2) void ctx_bf3(const float* __restrict__ scores,
                                                  const float* __restrict__ Edist,
                                                  const float* __restrict__ invrs,
                                                  const unsigned short* __restrict__ VhT,
                                                  const unsigned short* __restrict__ VlT,
                                                  unsigned short* __restrict__ Ch,
                                                  unsigned short* __restrict__ Cl) {
  __shared__ __align__(16) unsigned short Ah[128 * 32], Al[128 * 32];
  __shared__ __align__(16) unsigned short Bh[2][256 * 32], Bl[2][256 * 32];
  int z = blockIdx.z, b = z >> 3, h = z & 7;
  const float* Sb = scores + (long long)b * SQ * SQ;
  const unsigned short* Vh = VhT + (long long)b * EE * SQ;
  const unsigned short* Vl = VlT + (long long)b * EE * SQ;
  unsigned short* Chb = Ch + (long long)b * SQ * (NH * EE) + h * EE;
  unsigned short* Clb = Cl + (long long)b * SQ * (NH * EE) + h * EE;
  const float* Ez = Edist + (long long)z * SQ;
  int m0 = blockIdx.y * 128, n0 = blockIdx.x * 256;
  int tid = threadIdx.x;
  int wave = tid >> 6, lane = tid & 63;
  int quad = lane >> 4, l16 = lane & 15;
  int wr = wave >> 1, wc = wave & 1;  // wave-tile 64x128 (r6 mapping)
  f32x4 acc[4][8];
#pragma unroll
  for (int mf = 0; mf < 4; mf++)
#pragma unroll
    for (int nf = 0; nf < 8; nf++) acc[mf][nf] = (f32x4)(0.f);

  int aam = tid & 127, aakc = tid >> 7;
  float ei = Ez[m0 + aam];
  float inv = invrs[(long long)z * SQ + m0 + aam];
  float ci = ei * inv;
  const float* Srow = Sb + (long long)(m0 + aam) * SQ;
  int offA[2];
#pragma unroll
  for (int cc = 0; cc < 2; cc++) {
    int c = aakc * 2 + cc;
    offA[cc] = aam * 32 + ((c ^ ((aam >> 1) & 3)) * 8);
  }

  const unsigned short* gB = (wave < 2) ? Vh : Vl;
  long long gbase[8];
  int ldsq[8];
#pragma unroll
  for (int i = 0; i < 8; i++) {
    int qt = (wave & 1) * 8 + i;
    int row = qt * 16 + (lane >> 2);
    int cG = (lane & 3) ^ ((row >> 1) & 3);  // source-side XOR, linear dest
    gbase[i] = (long long)(n0 + row) * SQ + cG * 8;
    ldsq[i] = qt * 512;
  }

  int aoff[4], boff[8];
#pragma unroll
  for (int mf = 0; mf < 4; mf++) {
    int ra = wr * 64 + mf * 16 + l16;
    aoff[mf] = ra * 32 + ((quad ^ ((ra >> 1) & 3)) * 8);
  }
#pragma unroll
  for (int nf = 0; nf < 8; nf++) {
    int rb = wc * 128 + nf * 16 + l16;
    boff[nf] = rb * 32 + ((quad ^ ((rb >> 1) & 3)) * 8);
  }

  float4 s4r[4], e4r[4];
  uint4 aHc[2], aLc[2];
  auto loadA = [&](int kb) {
#pragma unroll
    for (int r = 0; r < 4; r++) {
      int kc = aakc * 4 + r;
      s4r[r] = *(const float4*)(Srow + kb + kc * 4);
      e4r[r] = *(const float4*)(Ez + kb + kc * 4);
    }
  };
  auto gateA = [&]() {
#pragma unroll
    for (int r = 0; r < 4; r++) {
      float4 s4 = s4r[r], e4 = e4r[r];
      float ax = (s4.x * ci) * __builtin_amdgcn_rcpf(ei + e4.x);
      float ay = (s4.y * ci) * __builtin_amdgcn_rcpf(ei + e4.y);
      float az = (s4.z * ci) * __builtin_amdgcn_rcpf(ei + e4.z);
      float aw = (s4.w * ci) * __builtin_amdgcn_rcpf(ei + e4.w);
      unsigned h01 = cvtpk(ax, ay), h23 = cvtpk(az, aw);
      float hx = bitf(h01 << 16), hy = bitf(h01 & 0xffff0000u);
      float hz = bitf(h23 << 16), hw = bitf(h23 & 0xffff0000u);
      unsigned l01 = cvtpk(ax - hx, ay - hy), l23 = cvtpk(az - hz, aw - hw);
      if ((r & 1) == 0) {
        aHc[r >> 1].x = h01; aHc[r >> 1].y = h23;
        aLc[r >> 1].x = l01; aLc[r >> 1].y = l23;
      } else {
        aHc[r >> 1].z = h01; aHc[r >> 1].w = h23;
        aLc[r >> 1].z = l01; aLc[r >> 1].w = l23;
      }
    }
  };
  auto stageB = [&](int buf, int kb) {
    unsigned short* base = (wave < 2) ? &Bh[buf][0] : &Bl[buf][0];
#pragma unroll
    for (int i = 0; i < 8; i++)
      __builtin_amdgcn_global_load_lds((glb_u32*)(gB + gbase[i] + kb),
                                       (lds_u32*)(base + ldsq[i]), 16, 0, 0);
  };

  loadA(0);
  gateA();
  stageB(0, 0);
  constexpr int NT = SQ / 32;
  for (int t = 0; t < NT; t++) {
    int cur = t & 1;
    __builtin_amdgcn_s_barrier();
#pragma unroll
    for (int cc = 0; cc < 2; cc++) {
      *(uint4*)&Ah[offA[cc]] = aHc[cc];
      *(uint4*)&Al[offA[cc]] = aLc[cc];
    }
    int kn = (t + 1 < NT) ? (t + 1) * 32 : t * 32;
    loadA(kn);
    stageB(cur ^ 1, kn);
    asm volatile("s_waitcnt lgkmcnt(0)" ::: "memory");
    asm volatile("s_waitcnt vmcnt(16)" ::: "memory");
    __builtin_amdgcn_s_barrier();
    __builtin_amdgcn_sched_barrier(0);
    gateA();
    bfrag ah[4], al_[4];
#pragma unroll
    for (int mf = 0; mf < 4; mf++) {
      ah[mf] = *(const bfrag*)&Ah[aoff[mf]];
      al_[mf] = *(const bfrag*)&Al[aoff[mf]];
    }
#pragma unroll
    for (int nf = 0; nf < 8; nf++) {
      bfrag bh = *(const bfrag*)&Bh[cur][boff[nf]];
      bfrag bl = *(const bfrag*)&Bl[cur][boff[nf]];
#pragma unroll
      for (int mf = 0; mf < 4; mf++) {
        acc[mf][nf] = __builtin_amdgcn_mfma_f32_16x16x32_bf16(al_[mf], bh, acc[mf][nf], 0, 0, 0);
        acc[mf][nf] = __builtin_amdgcn_mfma_f32_16x16x32_bf16(ah[mf], bl, acc[mf][nf], 0, 0, 0);
        acc[mf][nf] = __builtin_amdgcn_mfma_f32_16x16x32_bf16(ah[mf], bh, acc[mf][nf], 0, 0, 0);
      }
    }
    __builtin_amdgcn_sched_barrier(0);
  }
#pragma unroll
  for (int mf = 0; mf < 4; mf++) {
#pragma unroll
    for (int nf = 0; nf < 8; nf++) {
      int col = n0 + wc * 128 + nf * 16 + l16;
#pragma unroll
      for (int r = 0; r < 4; r++) {
        int row = m0 + wr * 64 + mf * 16 + quad * 4 + r;
        float o = acc[mf][nf][r];
        unsigned short hh = f2bf(o);
        Chb[(long long)row * (NH * EE) + col] = hh;
        Clb[(long long)row * (NH * EE) + col] = f2bf(o - bf2f(hh));
      }
    }
  }
}

// ================= bf16x3 MFMA NT-GEMM, pre-split operands, DMA-staged, WIDE =================
template <int ACT, int OUTM>
__global__ __launch_bounds__(256) void gemm_bf3w(
    const unsigned short* __restrict__ Ah_g, const unsigned short* __restrict__ Al_g, int lda,
    const unsigned short* __restrict__ Bh_g, const unsigned short* __restrict__ Bl_g, int ldb,
    const float* __restrict__ bias, const float* __restrict__ Res,
    float* __restrict__ C, unsigned short* __restrict__ Ch, unsigned short* __restrict__ Cl,
    int ldc, int K) {
  __shared__ __align__(16) unsigned short lds[3 * 12288];  // 3 bufs x 24 KB
  int gx = gridDim.x;
  int nwg = gx * (int)gridDim.y;
  int lin = blockIdx.y * gx + blockIdx.x;
  int cpx = nwg >> 3;
  int tl = (lin & 7) * cpx + (lin >> 3);
  int bx = tl % gx, by = tl / gx;
  int m0 = by * 128, n0 = bx * 64;
  int tid = threadIdx.x, wave = tid >> 6, lane = tid & 63;
  int quad = lane >> 4, l16 = lane & 15;

  const unsigned short* gptr[6];
  int ldsoff[6];
#pragma unroll
  for (int i = 0; i < 6; i++) {
    int d = wave * 6 + i;
    const unsigned short* src;
    int rowbase, ld, tb, qt;
    if (d < 8)       { src = Ah_g; rowbase = m0; ld = lda; tb = 0;     qt = d; }
    else if (d < 16) { src = Al_g; rowbase = m0; ld = lda; tb = 4096;  qt = d - 8; }
    else if (d < 20) { src = Bh_g; rowbase = n0; ld = ldb; tb = 8192;  qt = d - 16; }
    else             { src = Bl_g; rowbase = n0; ld = ldb; tb = 10240; qt = d - 20; }
    int row = qt * 16 + (lane >> 2);
    int cG = (lane & 3) ^ ((row >> 1) & 3);
    gptr[i] = src + (long long)(rowbase + row) * ld + cG * 8;
    ldsoff[i] = tb + qt * 512;
  }

  auto stage = [&](int buf, int kb) {
#pragma unroll
    for (int i = 0; i < 6; i++)
      __builtin_amdgcn_global_load_lds((glb_u32*)(gptr[i] + kb),
                                       (lds_u32*)&lds[buf * 12288 + ldsoff[i]], 16, 0, 0);
  };

  int aoff[4], boff[2];
#pragma unroll
  for (int mf = 0; mf < 4; mf++) {
    int r = (wave >> 1) * 64 + mf * 16 + l16;
    aoff[mf] = r * 32 + ((quad ^ ((r >> 1) & 3)) * 8);
  }
#pragma unroll
  for (int nf = 0; nf < 2; nf++) {
    int r = (wave & 1) * 32 + nf * 16 + l16;
    boff[nf] = r * 32 + ((quad ^ ((r >> 1) & 3)) * 8);
  }

  f32x4 acc[4][2];
#pragma unroll
  for (int mf = 0; mf < 4; mf++)
#pragma unroll
    for (int nf = 0; nf < 2; nf++) acc[mf][nf] = (f32x4)(0.f);

  int NT = K >> 5;
  stage(0, 0);
  stage(1, 32);
  int cur = 0;
  for (int t = 0; t < NT; t++) {
    int nb = cur + 2; if (nb >= 3) nb -= 3;
    int kf = (t + 2 < NT) ? (t + 2) * 32 : (NT - 1) * 32;  // tail: dummy (unread buffer)
    stage(nb, kf);
    asm volatile("s_waitcnt vmcnt(12)" ::: "memory");
    __builtin_amdgcn_s_barrier();
    __builtin_amdgcn_sched_barrier(0);
    const unsigned short* L = &lds[cur * 12288];
    bfrag bh[2], bl[2];
#pragma unroll
    for (int nf = 0; nf < 2; nf++) {
      bh[nf] = *(const bfrag*)&L[8192 + boff[nf]];
      bl[nf] = *(const bfrag*)&L[10240 + boff[nf]];
    }
#pragma unroll
    for (int mf = 0; mf < 4; mf++) {
      bfrag ah = *(const bfrag*)&L[aoff[mf]];
      bfrag al = *(const bfrag*)&L[4096 + aoff[mf]];
#pragma unroll
      for (int nf = 0; nf < 2; nf++) {
        acc[mf][nf] = __builtin_amdgcn_mfma_f32_16x16x32_bf16(al, bh[nf], acc[mf][nf], 0, 0, 0);
        acc[mf][nf] = __builtin_amdgcn_mfma_f32_16x16x32_bf16(ah, bl[nf], acc[mf][nf], 0, 0, 0);
        acc[mf][nf] = __builtin_amdgcn_mfma_f32_16x16x32_bf16(ah, bh[nf], acc[mf][nf], 0, 0, 0);
      }
    }
    __builtin_amdgcn_sched_barrier(0);
    __builtin_amdgcn_s_barrier();
    cur++; if (cur >= 3) cur -= 3;
  }

  // epilogue: C/D layout row = quad*4 + r, col = l16
#pragma unroll
  for (int mf = 0; mf < 4; mf++) {
#pragma unroll
    for (int nf = 0; nf < 2; nf++) {
      int col = n0 + (wave & 1) * 32 + nf * 16 + l16;
      float bi = bias ? bias[col] : 0.f;
#pragma unroll
      for (int r = 0; r < 4; r++) {
        int row = m0 + (wave >> 1) * 64 + mf * 16 + quad * 4 + r;
        float o = acc[mf][nf][r] + bi;
        if (ACT == 1) o = gelu_exact(o);
        if (OUTM == 0) {
          if (Res) o = o + Res[(long long)row * ldc + col];
          C[(long long)row * ldc + col] = o;
        } else {
          unsigned short hh = f2bf(o);
          Ch[(long long)row * ldc + col] = hh;
          Cl[(long long)row * ldc + col] = f2bf(o - bf2f(hh));
        }
      }
    }
  }
}

extern "C" void kernel_launch(void* const* d_in, const int* in_sizes, int n_in,
                              void* d_out, int out_size, void* d_ws, size_t ws_size,
                              hipStream_t stream) {
  const float* query     = (const float*)d_in[0];
  const float* ln1_g     = (const float*)d_in[1];
  const float* ln1_b     = (const float*)d_in[2];
  const float* in_proj_w = (const float*)d_in[3];
  const float* in_proj_b = (const float*)d_in[4];
  const float* out_w     = (const float*)d_in[5];
  const float* out_b     = (const float*)d_in[6];
  const float* conv_w    = (const float*)d_in[7];
  const float* conv_b    = (const float*)d_in[8];
  const float* ln2_g     = (const float*)d_in[9];
  const float* ln2_b     = (const float*)d_in[10];
  const float* mlp_w1    = (const float*)d_in[11];
  const float* mlp_b1    = (const float*)d_in[12];
  const float* mlp_w2    = (const float*)d_in[13];
  const float* mlp_b2    = (const float*)d_in[14];
  float* out = (float*)d_out;
  char* ws = (char*)d_ws;

  // Round-4/6 proven workspace layout (peak 112.25 MiB). Lifetime-disjoint reuse:
  float* nq     = (float*)(ws + 0);                      // [0,8)   dead after step 3
  float* qkv    = (float*)(ws + (8ull << 20));           // [8,32)  dead after step 4
  float* dist   = (float*)(ws + (32ull << 20));          // 128 KiB
  float* invrs  = (float*)(ws + (32ull << 20) + 131072); // 128 KiB
  float* scores = (float*)(ws + (32ull << 20) + 262144); // [32.25,48.25) dead after step 6
  unsigned short* VhT = (unsigned short*)(ws + 0);             // over dead nq, 4 MiB (3b-6)
  unsigned short* VlT = (unsigned short*)(ws + (4ull << 20));  // 4 MiB
  // ctx pre-split: [48.25,112.25)
  unsigned short* ctxh = (unsigned short*)(ws + (48ull << 20) + 262144);  // 32 MiB
  unsigned short* ctxl = (unsigned short*)(ws + (80ull << 20) + 262144);  // 32 MiB
  // weight splits in dead scores region (written 6b, live to 10):
  unsigned short* out_wh = (unsigned short*)(ws + (32ull << 20) + 262144);  // 4 MiB
  unsigned short* out_wl = out_wh + 2097152;                                // 4 MiB
  unsigned short* w1h    = out_wl + 2097152;                                // 2 MiB
  unsigned short* w1l    = w1h + 1048576;                                   // 2 MiB
  unsigned short* w2h    = w1l + 1048576;                                   // 2 MiB
  unsigned short* w2l    = w2h + 1048576;                                   // 2 MiB (ends at 48.25)
  // LN2 split over dead ctxh (after step 7):
  unsigned short* ln2h = (unsigned short*)(ws + (48ull << 20) + 262144);  // 4 MiB
  unsigned short* ln2l = ln2h + 2097152;                                  // 4 MiB
  // MLP hidden split over dead nq+qkv (after step 6):
  unsigned short* hbufh = (unsigned short*)(ws + 0);        // 16 MiB
  unsigned short* hbufl = hbufh + 8388608;                  // 16 MiB (ends at 32)
  // Edist (128 KiB) lives in d_out scratch: written step 2, read step 6;
  // step 7 (stream-ordered after 6) overwrites out with the real output.
  float* Edist = (float*)d_out;

  // 1. LN1 (frozen)
  ln_np<<<dim3(NB * SQ), 64, 0, stream>>>(query, ln1_g, ln1_b, nq);
  // 2. distances (frozen) + E = __expf(dist) for ctx gate
  dist_np<<<dim3(NB * NH, 4), 256, 0, stream>>>(nq, conv_w, conv_b, dist, Edist);
  // 3. qkv (frozen chain, 64x128 tile)  M=4096 N=1536 K=512
  gemm_nt3<0, 384><<<dim3(12, 64, 1), 256, 0, stream>>>(nq, EE, 0, in_proj_w, EE, 0,
                                                        in_proj_b, nullptr, qkv, 3 * EE, 0, EE, 1.f);
  // 3b. V transpose + bf16 hi/lo split
  vsplit_t<<<dim3(16, 8, NB), 256, 0, stream>>>(qkv, VhT, VlT);
  // 4. scores (frozen chain + true division, 64x128 tile)  M=N=1024 K=512, batched B
  gemm_nt3<2, 384><<<dim3(8, 16, NB), 256, 0, stream>>>(
      qkv, 3 * EE, (long long)SQ * 3 * EE, qkv + EE, 3 * EE, (long long)SQ * 3 * EE,
      nullptr, nullptr, scores, SQ, (long long)SQ * SQ, EE, sqrtf(512.0f));
  // 5. gated row sums (frozen, fp64 exp)
  rowsum_np<<<dim3(SQ, NB * NH), 64, 0, stream>>>(scores, dist, invrs);
  // 6. ctx via bf16x3 MFMA, 128x256 tile, B-DMA + XOR LDS  M=1024 N=512 K=1024
  ctx_bf3<<<dim3(2, 8, NB * NH), 256, 0, stream>>>(scores, Edist, invrs, VhT, VlT, ctxh, ctxl);
  // 6b. weight splits (scores region is dead now)
  wsplit<<<dim3(2048), 256, 0, stream>>>(out_w, out_wh, out_wl, 524288);
  wsplit<<<dim3(1024), 256, 0, stream>>>(mlp_w1, w1h, w1l, 262144);
  wsplit<<<dim3(1024), 256, 0, stream>>>(mlp_w2, w2h, w2l, 262144);
  // 7. attn_out + residual (wide DMA bf16x3)  M=4096 N=512 K=4096
  gemm_bf3w<0, 0><<<dim3(8, 32), 256, 0, stream>>>(ctxh, ctxl, NH * EE, out_wh, out_wl, NH * EE,
                                                   out_b, query, out, nullptr, nullptr,
                                                   EE, NH * EE);
  // 8. LN2, split output
  ln_np_s<<<dim3(NB * SQ), 64, 0, stream>>>(out, ln2_g, ln2_b, ln2h, ln2l);
  // 9. MLP1 + gelu, split output (wide DMA bf16x3)  M=4096 N=2048 K=512
  gemm_bf3w<1, 1><<<dim3(32, 32), 256, 0, stream>>>(ln2h, ln2l, EE, w1h, w1l, EE,
                                                    mlp_b1, nullptr, nullptr, hbufh, hbufl,
                                                    4 * EE, EE);
  // 10. MLP2 + residual (wide DMA bf16x3)  M=4096 N=512 K=2048
  gemm_bf3w<0, 0><<<dim3(8, 32), 256, 0, stream>>>(hbufh, hbufl, 4 * EE, w2h, w2l, 4 * EE,
                                                   mlp_b2, out, out, nullptr, nullptr,
                                                   EE, 4 * EE);
}

// Round 11
// 620.213 us; speedup vs baseline: 1.0538x; 1.0538x over previous
//
#include <hip/hip_runtime.h>
#include <math.h>

#define SQ 1024  // S
#define EE 512   // E
#define NB 4     // B
#define NH 8     // H

typedef __attribute__((ext_vector_type(8))) short bfrag;       // 8 bf16 (4 VGPRs)
typedef __attribute__((ext_vector_type(4))) float f32x4;       // MFMA C/D
typedef __attribute__((ext_vector_type(4))) unsigned short u16x4;
typedef __attribute__((ext_vector_type(8))) unsigned short u16x8;

typedef __attribute__((address_space(3))) unsigned int lds_u32;
typedef const __attribute__((address_space(1))) unsigned int glb_u32;

// Optimization barrier: forces materialization (rounding) so the compiler
// cannot FMA-contract or reassociate across numpy's op boundaries.
__device__ __forceinline__ float sep(float x) {
  asm volatile("" : "+v"(x));
  return x;
}

__device__ __forceinline__ unsigned short f2bf(float f) {
  unsigned u = __builtin_bit_cast(unsigned, f);
  unsigned r = (u + 0x7fffu + ((u >> 16) & 1u)) >> 16;
  return (unsigned short)r;
}
__device__ __forceinline__ float bf2f(unsigned short h) {
  unsigned u = ((unsigned)h) << 16;
  return __builtin_bit_cast(float, u);
}
__device__ __forceinline__ float bitf(unsigned u) { return __builtin_bit_cast(float, u); }

// packed f32x2 -> bf16x2 (lo16 = bf16(a), hi16 = bf16(b))
__device__ __forceinline__ unsigned cvtpk(float a, float b) {
  unsigned r;
  asm("v_cvt_pk_bf16_f32 %0, %1, %2" : "=v"(r) : "v"(a), "v"(b));
  return r;
}

__device__ __forceinline__ void split4(float4 v, u16x4& h, u16x4& l) {
  h.x = f2bf(v.x); l.x = f2bf(v.x - bf2f(h.x));
  h.y = f2bf(v.y); l.y = f2bf(v.y - bf2f(h.y));
  h.z = f2bf(v.z); l.z = f2bf(v.z - bf2f(h.z));
  h.w = f2bf(v.w); l.w = f2bf(v.w - bf2f(h.w));
}

// ================= LayerNorm, numpy-exact fp32 (np.mean pairwise) — FROZEN =================
__global__ __launch_bounds__(64) void ln_np(const float* __restrict__ x,
                                            const float* __restrict__ g,
                                            const float* __restrict__ b,
                                            float* __restrict__ y) {
  __shared__ float xs[EE];
  __shared__ float bc[2];
  long long t = blockIdx.x;
  int lane = threadIdx.x;
#pragma unroll
  for (int m = 0; m < 8; m++) xs[lane + 64 * m] = x[t * EE + lane + 64 * m];
  __syncthreads();
  int l = lane >> 3, a = lane & 7;
  float r = 0.f;
  if (lane < 32) {
    r = xs[l * 128 + a];
#pragma unroll
    for (int m = 1; m < 16; m++) r = r + xs[l * 128 + 8 * m + a];
  }
  r = r + __shfl_xor(r, 1);
  r = r + __shfl_xor(r, 2);
  r = r + __shfl_xor(r, 4);
  r = r + __shfl_xor(r, 8);
  r = r + __shfl_xor(r, 16);
  if (lane == 0) bc[0] = r / 512.0f;
  __syncthreads();
  float mean = bc[0];
  r = 0.f;
  if (lane < 32) {
#pragma unroll
    for (int m = 0; m < 16; m++) {
      float d = sep(xs[l * 128 + 8 * m + a] - mean);
      float s2 = sep(d * d);
      r = (m == 0) ? s2 : (r + s2);
    }
  }
  r = r + __shfl_xor(r, 1);
  r = r + __shfl_xor(r, 2);
  r = r + __shfl_xor(r, 4);
  r = r + __shfl_xor(r, 8);
  r = r + __shfl_xor(r, 16);
  if (lane == 0) bc[1] = r / 512.0f;
  __syncthreads();
  float var = bc[1];
  float rs = 1.0f / sqrtf(var + 1e-5f);
#pragma unroll
  for (int m = 0; m < 8; m++) {
    int i = lane + 64 * m;
    float d = sep(xs[i] - mean);
    float t1 = sep(d * rs);
    float t2 = sep(t1 * g[i]);
    y[t * EE + i] = t2 + b[i];
  }
}

// ===== LayerNorm (LN2) with split bf16 hi/lo output (same frozen math, split store) =====
__global__ __launch_bounds__(64) void ln_np_s(const float* __restrict__ x,
                                              const float* __restrict__ g,
                                              const float* __restrict__ b,
                                              unsigned short* __restrict__ yh,
                                              unsigned short* __restrict__ yl) {
  __shared__ float xs[EE];
  __shared__ float bc[2];
  long long t = blockIdx.x;
  int lane = threadIdx.x;
#pragma unroll
  for (int m = 0; m < 8; m++) xs[lane + 64 * m] = x[t * EE + lane + 64 * m];
  __syncthreads();
  int l = lane >> 3, a = lane & 7;
  float r = 0.f;
  if (lane < 32) {
    r = xs[l * 128 + a];
#pragma unroll
    for (int m = 1; m < 16; m++) r = r + xs[l * 128 + 8 * m + a];
  }
  r = r + __shfl_xor(r, 1);
  r = r + __shfl_xor(r, 2);
  r = r + __shfl_xor(r, 4);
  r = r + __shfl_xor(r, 8);
  r = r + __shfl_xor(r, 16);
  if (lane == 0) bc[0] = r / 512.0f;
  __syncthreads();
  float mean = bc[0];
  r = 0.f;
  if (lane < 32) {
#pragma unroll
    for (int m = 0; m < 16; m++) {
      float d = sep(xs[l * 128 + 8 * m + a] - mean);
      float s2 = sep(d * d);
      r = (m == 0) ? s2 : (r + s2);
    }
  }
  r = r + __shfl_xor(r, 1);
  r = r + __shfl_xor(r, 2);
  r = r + __shfl_xor(r, 4);
  r = r + __shfl_xor(r, 8);
  r = r + __shfl_xor(r, 16);
  if (lane == 0) bc[1] = r / 512.0f;
  __syncthreads();
  float var = bc[1];
  float rs = 1.0f / sqrtf(var + 1e-5f);
#pragma unroll
  for (int m = 0; m < 8; m++) {
    int i = lane + 64 * m;
    float d = sep(xs[i] - mean);
    float t1 = sep(d * rs);
    float t2 = sep(t1 * g[i]);
    float o = t2 + b[i];
    unsigned short hh = f2bf(o);
    yh[t * EE + i] = hh;
    yl[t * EE + i] = f2bf(o - bf2f(hh));
  }
}

// ================= distances — FROZEN math; also emits E = __expf(dist) for ctx gate =================
__global__ __launch_bounds__(256) void dist_np(const float* __restrict__ nq,
                                               const float* __restrict__ conv_w,
                                               const float* __restrict__ conv_b,
                                               float* __restrict__ dist,
                                               float* __restrict__ Edist) {
  int bh = blockIdx.x;
  int b = bh >> 3, h = bh & 7;
  float cb = conv_b[h];
  const float* W = conv_w + (long long)h * EE * 3;
  int s = blockIdx.y * 256 + threadIdx.x;
  float d = cb;
#pragma unroll
  for (int k = 0; k < 3; k++) {
    int t = s - 2 + k;
    if (t < 0) continue;
    const float* row = nq + ((long long)b * SQ + t) * EE;
    float acc = 0.f;
    for (int e = 0; e < EE; e++) acc = __builtin_fmaf(row[e], W[e * 3 + k], acc);
    d = sep(d + acc);
  }
  float dv = (float)tanh((double)d);
  dist[(long long)bh * SQ + s] = dv;
  Edist[(long long)bh * SQ + s] = __expf(dv);  // d in [-1,1]: no overflow; numerator-only use
}

__device__ __forceinline__ float gelu_exact(float x) {
  return 0.5f * x * (1.f + erff(x / 1.41421356237309504880f));
}

// ============ fp32 tiled NT-GEMM, 128x128 tile / 8x8 micro — FROZEN per-output chain (r9) ============
template <int ACT, int SPLITK>
__global__ __launch_bounds__(256) void gemm_nt2(const float* __restrict__ A, int lda, long long sA,
                                                const float* __restrict__ B, int ldb, long long sB,
                                                const float* __restrict__ bias,
                                                const float* __restrict__ Res,
                                                float* __restrict__ C, int ldc, long long sC,
                                                int K, float alpha) {
  __shared__ float As[16][132];
  __shared__ float Bs[16][132];
  int z = blockIdx.z;
  A += (long long)z * sA;
  B += (long long)z * sB;
  C += (long long)z * sC;
  if (Res) Res += (long long)z * sC;
  int gx = gridDim.x;
  int nwg = gx * (int)gridDim.y;
  int lin = blockIdx.y * gx + blockIdx.x;
  int cpx = nwg >> 3;
  int tl = (lin & 7) * cpx + (lin >> 3);
  int bx = tl % gx, by = tl / gx;
  int m0 = by * 128, n0 = bx * 128;
  int tid = threadIdx.x;
  int lr = tid >> 2, lc = tid & 3;
  int tx = tid & 15, ty = tid >> 4;
  float acc[8][8] = {};
  float acc2[8][8] = {};
  const float* Arow0 = A + (long long)(m0 + lr) * lda + lc * 4;
  const float* Arow1 = A + (long long)(m0 + 64 + lr) * lda + lc * 4;
  const float* Brow0 = B + (long long)(n0 + lr) * ldb + lc * 4;
  const float* Brow1 = B + (long long)(n0 + 64 + lr) * ldb + lc * 4;
  float4 a4[2], b4[2];
  a4[0] = *(const float4*)(Arow0);
  a4[1] = *(const float4*)(Arow1);
  b4[0] = *(const float4*)(Brow0);
  b4[1] = *(const float4*)(Brow1);

  auto step = [&](int k0, float (*tgt)[8]) {
    __syncthreads();
    As[lc * 4 + 0][lr] = a4[0].x; As[lc * 4 + 1][lr] = a4[0].y;
    As[lc * 4 + 2][lr] = a4[0].z; As[lc * 4 + 3][lr] = a4[0].w;
    As[lc * 4 + 0][64 + lr] = a4[1].x; As[lc * 4 + 1][64 + lr] = a4[1].y;
    As[lc * 4 + 2][64 + lr] = a4[1].z; As[lc * 4 + 3][64 + lr] = a4[1].w;
    Bs[lc * 4 + 0][lr] = b4[0].x; Bs[lc * 4 + 1][lr] = b4[0].y;
    Bs[lc * 4 + 2][lr] = b4[0].z; Bs[lc * 4 + 3][lr] = b4[0].w;
    Bs[lc * 4 + 0][64 + lr] = b4[1].x; Bs[lc * 4 + 1][64 + lr] = b4[1].y;
    Bs[lc * 4 + 2][64 + lr] = b4[1].z; Bs[lc * 4 + 3][64 + lr] = b4[1].w;
    __syncthreads();
    int kn = (k0 + 16 < K) ? (k0 + 16) : k0;
    a4[0] = *(const float4*)(Arow0 + kn);
    a4[1] = *(const float4*)(Arow1 + kn);
    b4[0] = *(const float4*)(Brow0 + kn);
    b4[1] = *(const float4*)(Brow1 + kn);
#pragma unroll
    for (int kk = 0; kk < 16; kk++) {
      float4 av0 = *(const float4*)&As[kk][ty * 4];
      float4 av1 = *(const float4*)&As[kk][64 + ty * 4];
      float4 bv0 = *(const float4*)&Bs[kk][tx * 4];
      float4 bv1 = *(const float4*)&Bs[kk][64 + tx * 4];
      float a[8] = {av0.x, av0.y, av0.z, av0.w, av1.x, av1.y, av1.z, av1.w};
      float bb[8] = {bv0.x, bv0.y, bv0.z, bv0.w, bv1.x, bv1.y, bv1.z, bv1.w};
#pragma unroll
      for (int i = 0; i < 8; i++)
#pragma unroll
        for (int j = 0; j < 8; j++) tgt[i][j] += a[i] * bb[j];
    }
  };

  int k0 = 0;
  if (SPLITK > 0) {
    for (; k0 < SPLITK; k0 += 16) step(k0, acc);
    for (; k0 < K; k0 += 16) step(k0, acc2);
#pragma unroll
    for (int i = 0; i < 8; i++)
#pragma unroll
      for (int j = 0; j < 8; j++) acc[i][j] = sep(acc[i][j]) + acc2[i][j];
  } else {
    for (; k0 < K; k0 += 16) step(k0, acc);
  }

  float4 bias4a = make_float4(0.f, 0.f, 0.f, 0.f);
  float4 bias4b = make_float4(0.f, 0.f, 0.f, 0.f);
  if (ACT != 2 && bias) {
    bias4a = *(const float4*)(bias + n0 + tx * 4);
    bias4b = *(const float4*)(bias + n0 + 64 + tx * 4);
  }
#pragma unroll
  for (int i = 0; i < 8; i++) {
    int row = m0 + ((i < 4) ? (ty * 4 + i) : (64 + ty * 4 + (i - 4)));
    float o[8];
    if (ACT == 2) {
#pragma unroll
      for (int j = 0; j < 8; j++) o[j] = acc[i][j] / alpha;
    } else {
      o[0] = sep(acc[i][0] * alpha) + bias4a.x;
      o[1] = sep(acc[i][1] * alpha) + bias4a.y;
      o[2] = sep(acc[i][2] * alpha) + bias4a.z;
      o[3] = sep(acc[i][3] * alpha) + bias4a.w;
      o[4] = sep(acc[i][4] * alpha) + bias4b.x;
      o[5] = sep(acc[i][5] * alpha) + bias4b.y;
      o[6] = sep(acc[i][6] * alpha) + bias4b.z;
      o[7] = sep(acc[i][7] * alpha) + bias4b.w;
    }
    if (ACT == 1) {
#pragma unroll
      for (int j = 0; j < 8; j++) o[j] = gelu_exact(o[j]);
    }
    if (Res) {
      float4 r4a = *(const float4*)(Res + (long long)row * ldc + n0 + tx * 4);
      float4 r4b = *(const float4*)(Res + (long long)row * ldc + n0 + 64 + tx * 4);
      o[0] = sep(o[0]) + r4a.x; o[1] = sep(o[1]) + r4a.y;
      o[2] = sep(o[2]) + r4a.z; o[3] = sep(o[3]) + r4a.w;
      o[4] = sep(o[4]) + r4b.x; o[5] = sep(o[5]) + r4b.y;
      o[6] = sep(o[6]) + r4b.z; o[7] = sep(o[7]) + r4b.w;
    }
    *(float4*)(C + (long long)row * ldc + n0 + tx * 4) = make_float4(o[0], o[1], o[2], o[3]);
    *(float4*)(C + (long long)row * ldc + n0 + 64 + tx * 4) = make_float4(o[4], o[5], o[6], o[7]);
  }
}

// ============ fp32 tiled NT-GEMM, 64x192 tile / 4x12 micro — FROZEN per-output chain ============
// Balanced grid (512 blocks = exactly 2 blocks/CU for qkv), 48 FMA / 4 LDS-reads
// per kk. Per-output chain bit-identical to gemm_nt: same k order, same += a*b,
// two-loop SPLITK, same sep() epilogue. Col groups {tx*4, 64+tx*4, 128+tx*4}.
template <int ACT, int SPLITK>
__global__ __launch_bounds__(256) void gemm_nt4(const float* __restrict__ A, int lda, long long sA,
                                                const float* __restrict__ B, int ldb, long long sB,
                                                const float* __restrict__ bias,
                                                const float* __restrict__ Res,
                                                float* __restrict__ C, int ldc, long long sC,
                                                int K, float alpha) {
  __shared__ float As[16][68];
  __shared__ float Bs[16][196];
  int z = blockIdx.z;
  A += (long long)z * sA;
  B += (long long)z * sB;
  C += (long long)z * sC;
  if (Res) Res += (long long)z * sC;
  int gx = gridDim.x;
  int nwg = gx * (int)gridDim.y;
  int lin = blockIdx.y * gx + blockIdx.x;
  int cpx = nwg >> 3;
  int tl = (lin & 7) * cpx + (lin >> 3);
  int bx = tl % gx, by = tl / gx;
  int m0 = by * 64, n0 = bx * 192;
  int tid = threadIdx.x;
  int lr = tid >> 2, lc = tid & 3;
  int tx = tid & 15, ty = tid >> 4;
  float acc[4][12] = {};
  float acc2[4][12] = {};
  const float* Arow  = A + (long long)(m0 + lr) * lda + lc * 4;
  const float* Brow0 = B + (long long)(n0 + lr) * ldb + lc * 4;
  const float* Brow1 = B + (long long)(n0 + 64 + lr) * ldb + lc * 4;
  const float* Brow2 = B + (long long)(n0 + 128 + lr) * ldb + lc * 4;
  float4 a4, b4[3];
  a4 = *(const float4*)(Arow);
  b4[0] = *(const float4*)(Brow0);
  b4[1] = *(const float4*)(Brow1);
  b4[2] = *(const float4*)(Brow2);

  auto step = [&](int k0, float (*tgt)[12]) {
    __syncthreads();
    As[lc * 4 + 0][lr] = a4.x; As[lc * 4 + 1][lr] = a4.y;
    As[lc * 4 + 2][lr] = a4.z; As[lc * 4 + 3][lr] = a4.w;
    Bs[lc * 4 + 0][lr] = b4[0].x; Bs[lc * 4 + 1][lr] = b4[0].y;
    Bs[lc * 4 + 2][lr] = b4[0].z; Bs[lc * 4 + 3][lr] = b4[0].w;
    Bs[lc * 4 + 0][64 + lr] = b4[1].x; Bs[lc * 4 + 1][64 + lr] = b4[1].y;
    Bs[lc * 4 + 2][64 + lr] = b4[1].z; Bs[lc * 4 + 3][64 + lr] = b4[1].w;
    Bs[lc * 4 + 0][128 + lr] = b4[2].x; Bs[lc * 4 + 1][128 + lr] = b4[2].y;
    Bs[lc * 4 + 2][128 + lr] = b4[2].z; Bs[lc * 4 + 3][128 + lr] = b4[2].w;
    __syncthreads();
    int kn = (k0 + 16 < K) ? (k0 + 16) : k0;
    a4 = *(const float4*)(Arow + kn);
    b4[0] = *(const float4*)(Brow0 + kn);
    b4[1] = *(const float4*)(Brow1 + kn);
    b4[2] = *(const float4*)(Brow2 + kn);
#pragma unroll
    for (int kk = 0; kk < 16; kk++) {
      float4 av = *(const float4*)&As[kk][ty * 4];
      float4 bv0 = *(const float4*)&Bs[kk][tx * 4];
      float4 bv1 = *(const float4*)&Bs[kk][64 + tx * 4];
      float4 bv2 = *(const float4*)&Bs[kk][128 + tx * 4];
      float a[4] = {av.x, av.y, av.z, av.w};
      float bb[12] = {bv0.x, bv0.y, bv0.z, bv0.w, bv1.x, bv1.y, bv1.z, bv1.w,
                      bv2.x, bv2.y, bv2.z, bv2.w};
#pragma unroll
      for (int i = 0; i < 4; i++)
#pragma unroll
        for (int j = 0; j < 12; j++) tgt[i][j] += a[i] * bb[j];
    }
  };

  int k0 = 0;
  if (SPLITK > 0) {
    for (; k0 < SPLITK; k0 += 16) step(k0, acc);
    for (; k0 < K; k0 += 16) step(k0, acc2);
#pragma unroll
    for (int i = 0; i < 4; i++)
#pragma unroll
      for (int j = 0; j < 12; j++) acc[i][j] = sep(acc[i][j]) + acc2[i][j];
  } else {
    for (; k0 < K; k0 += 16) step(k0, acc);
  }

  float4 bias4a = make_float4(0.f, 0.f, 0.f, 0.f);
  float4 bias4b = make_float4(0.f, 0.f, 0.f, 0.f);
  float4 bias4c = make_float4(0.f, 0.f, 0.f, 0.f);
  if (ACT != 2 && bias) {
    bias4a = *(const float4*)(bias + n0 + tx * 4);
    bias4b = *(const float4*)(bias + n0 + 64 + tx * 4);
    bias4c = *(const float4*)(bias + n0 + 128 + tx * 4);
  }
#pragma unroll
  for (int i = 0; i < 4; i++) {
    int row = m0 + ty * 4 + i;
    float o[12];
    if (ACT == 2) {
#pragma unroll
      for (int j = 0; j < 12; j++) o[j] = acc[i][j] / alpha;
    } else {
      o[0]  = sep(acc[i][0]  * alpha) + bias4a.x;
      o[1]  = sep(acc[i][1]  * alpha) + bias4a.y;
      o[2]  = sep(acc[i][2]  * alpha) + bias4a.z;
      o[3]  = sep(acc[i][3]  * alpha) + bias4a.w;
      o[4]  = sep(acc[i][4]  * alpha) + bias4b.x;
      o[5]  = sep(acc[i][5]  * alpha) + bias4b.y;
      o[6]  = sep(acc[i][6]  * alpha) + bias4b.z;
      o[7]  = sep(acc[i][7]  * alpha) + bias4b.w;
      o[8]  = sep(acc[i][8]  * alpha) + bias4c.x;
      o[9]  = sep(acc[i][9]  * alpha) + bias4c.y;
      o[10] = sep(acc[i][10] * alpha) + bias4c.z;
      o[11] = sep(acc[i][11] * alpha) + bias4c.w;
    }
    if (ACT == 1) {
#pragma unroll
      for (int j = 0; j < 12; j++) o[j] = gelu_exact(o[j]);
    }
    if (Res) {
      float4 r4a = *(const float4*)(Res + (long long)row * ldc + n0 + tx * 4);
      float4 r4b = *(const float4*)(Res + (long long)row * ldc + n0 + 64 + tx * 4);
      float4 r4c = *(const float4*)(Res + (long long)row * ldc + n0 + 128 + tx * 4);
      o[0] = sep(o[0]) + r4a.x; o[1] = sep(o[1]) + r4a.y;
      o[2] = sep(o[2]) + r4a.z; o[3] = sep(o[3]) + r4a.w;
      o[4] = sep(o[4]) + r4b.x; o[5] = sep(o[5]) + r4b.y;
      o[6] = sep(o[6]) + r4b.z; o[7] = sep(o[7]) + r4b.w;
      o[8] = sep(o[8]) + r4c.x; o[9] = sep(o[9]) + r4c.y;
      o[10] = sep(o[10]) + r4c.z; o[11] = sep(o[11]) + r4c.w;
    }
    *(float4*)(C + (long long)row * ldc + n0 + tx * 4) = make_float4(o[0], o[1], o[2], o[3]);
    *(float4*)(C + (long long)row * ldc + n0 + 64 + tx * 4) = make_float4(o[4], o[5], o[6], o[7]);
    *(float4*)(C + (long long)row * ldc + n0 + 128 + tx * 4) = make_float4(o[8], o[9], o[10], o[11]);
  }
}

// ================= gated row sums: np.sum pairwise(1024) — FROZEN (fp64 exp) =================
__global__ __launch_bounds__(64) void rowsum_np(const float* __restrict__ scores,
                                                const float* __restrict__ dist,
                                                float* __restrict__ invrs) {
  __shared__ float wsm[SQ];
  int i = blockIdx.x;
  int z = blockIdx.y;
  int b = z >> 3;
  const float* srow = scores + ((long long)b * SQ + i) * SQ;
  const float* dz = dist + (long long)z * SQ;
  float di = dz[i];
  int lane = threadIdx.x;
#pragma unroll
  for (int m = 0; m < 16; m++) {
    int j = lane + 64 * m;
    float e = (float)exp((double)(dz[j] - di));
    float gg = 1.f / (1.f + e);
    wsm[j] = srow[j] * gg;
  }
  __syncthreads();
  int l = lane >> 3, a = lane & 7;
  float r = wsm[l * 128 + a];
#pragma unroll
  for (int m = 1; m < 16; m++) r = r + wsm[l * 128 + 8 * m + a];
  r = r + __shfl_xor(r, 1);
  r = r + __shfl_xor(r, 2);
  r = r + __shfl_xor(r, 4);
  r = r + __shfl_xor(r, 8);
  r = r + __shfl_xor(r, 16);
  r = r + __shfl_xor(r, 32);
  if (lane == 0) invrs[(long long)z * SQ + i] = 1.f / (r + 1e-12f);
}

// ================= V transpose + bf16 hi/lo split:  VhT/VlT[b][e][j] = split(V[b][j][e]) =================
__global__ __launch_bounds__(256) void vsplit_t(const float* __restrict__ qkv,
                                                unsigned short* __restrict__ VhT,
                                                unsigned short* __restrict__ VlT) {
  __shared__ float tile[64][65];
  int b = blockIdx.z;
  int j0 = blockIdx.x * 64;  // S tile
  int e0 = blockIdx.y * 64;  // E tile
  const float* V = qkv + (long long)b * SQ * (3 * EE) + 2 * EE;
  unsigned short* Vh = VhT + (long long)b * EE * SQ;
  unsigned short* Vl = VlT + (long long)b * EE * SQ;
  int tx = threadIdx.x & 15, ty = threadIdx.x >> 4;
#pragma unroll
  for (int r = 0; r < 4; r++) {
    int j = j0 + ty + r * 16;
    float4 v = *(const float4*)(V + (long long)j * (3 * EE) + e0 + tx * 4);
    tile[ty + r * 16][tx * 4 + 0] = v.x;
    tile[ty + r * 16][tx * 4 + 1] = v.y;
    tile[ty + r * 16][tx * 4 + 2] = v.z;
    tile[ty + r * 16][tx * 4 + 3] = v.w;
  }
  __syncthreads();
#pragma unroll
  for (int r = 0; r < 4; r++) {
    int el = ty + r * 16;
    float4 f;
    f.x = tile[tx * 4 + 0][el];
    f.y = tile[tx * 4 + 1][el];
    f.z = tile[tx * 4 + 2][el];
    f.w = tile[tx * 4 + 3][el];
    u16x4 hh, ll;
    split4(f, hh, ll);
    long long o = (long long)(e0 + el) * SQ + j0 + tx * 4;
    *(u16x4*)(Vh + o) = hh;
    *(u16x4*)(Vl + o) = ll;
  }
}

// ===== flat fp32 -> bf16 hi/lo split (weights); n4 = count/4 =====
__global__ __launch_bounds__(256) void wsplit(const float* __restrict__ W,
                                              unsigned short* __restrict__ Wh,
                                              unsigned short* __restrict__ Wl, int n4) {
  int i = blockIdx.x * 256 + threadIdx.x;
  if (i >= n4) return;
  float4 v = *(const float4*)(W + (long long)i * 4);
  u16x4 h, l;
  split4(v, h, l);
  *(u16x4*)(Wh + (long long)i * 4) = h;
  *(u16x4*)(Wl + (long long)i * 4) = l;
}

// ================= ctx GEMM via bf16x3 MFMA — r6 geometry + B-DMA + XOR LDS (r8, proven) ==========
__global__ __launch_bounds__(256, 2) void ctx_bf3(const float* __restrict__ scores,
                                                  const float* __restrict__ Edist,
                                                  const float* __restrict__ invrs,
                                                  const unsigned short* __restrict__ VhT,
                                                  const unsigned short* __restrict__ VlT,
                                                  unsigned short* __restrict__ Ch,
                                                  unsigned short* __restrict__ Cl) {
  __shared__ __align__(16) unsigned short Ah[128 * 32], Al[128 * 32];
  __shared__ __align__(16) unsigned short Bh[2][256 * 32], Bl[2][256 * 32];
  int z = blockIdx.z, b = z >> 3, h = z & 7;
  const float* Sb = scores + (long long)b * SQ * SQ;
  const unsigned short* Vh = VhT + (long long)b * EE * SQ;
  const unsigned short* Vl = VlT + (long long)b * EE * SQ;
  unsigned short* Chb = Ch + (long long)b * SQ * (NH * EE) + h * EE;
  unsigned short* Clb = Cl + (long long)b * SQ * (NH * EE) + h * EE;
  const float* Ez = Edist + (long long)z * SQ;
  int m0 = blockIdx.y * 128, n0 = blockIdx.x * 256;
  int tid = threadIdx.x;
  int wave = tid >> 6, lane = tid & 63;
  int quad = lane >> 4, l16 = lane & 15;
  int wr = wave >> 1, wc = wave & 1;  // wave-tile 64x128 (r6 mapping)
  f32x4 acc[4][8];
#pragma unroll
  for (int mf = 0; mf < 4; mf++)
#pragma unroll
    for (int nf = 0; nf < 8; nf++) acc[mf][nf] = (f32x4)(0.f);

  int aam = tid & 127, aakc = tid >> 7;
  float ei = Ez[m0 + aam];
  float inv = invrs[(long long)z * SQ + m0 + aam];
  float ci = ei * inv;
  const float* Srow = Sb + (long long)(m0 + aam) * SQ;
  int offA[2];
#pragma unroll
  for (int cc = 0; cc < 2; cc++) {
    int c = aakc * 2 + cc;
    offA[cc] = aam * 32 + ((c ^ ((aam >> 1) & 3)) * 8);
  }

  const unsigned short* gB = (wave < 2) ? Vh : Vl;
  long long gbase[8];
  int ldsq[8];
#pragma unroll
  for (int i = 0; i < 8; i++) {
    int qt = (wave & 1) * 8 + i;
    int row = qt * 16 + (lane >> 2);
    int cG = (lane & 3) ^ ((row >> 1) & 3);  // source-side XOR, linear dest
    gbase[i] = (long long)(n0 + row) * SQ + cG * 8;
    ldsq[i] = qt * 512;
  }

  int aoff[4], boff[8];
#pragma unroll
  for (int mf = 0; mf < 4; mf++) {
    int ra = wr * 64 + mf * 16 + l16;
    aoff[mf] = ra * 32 + ((quad ^ ((ra >> 1) & 3)) * 8);
  }
#pragma unroll
  for (int nf = 0; nf < 8; nf++) {
    int rb = wc * 128 + nf * 16 + l16;
    boff[nf] = rb * 32 + ((quad ^ ((rb >> 1) & 3)) * 8);
  }

  float4 s4r[4], e4r[4];
  uint4 aHc[2], aLc[2];
  auto loadA = [&](int kb) {
#pragma unroll
    for (int r = 0; r < 4; r++) {
      int kc = aakc * 4 + r;
      s4r[r] = *(const float4*)(Srow + kb + kc * 4);
      e4r[r] = *(const float4*)(Ez + kb + kc * 4);
    }
  };
  auto gateA = [&]() {
#pragma unroll
    for (int r = 0; r < 4; r++) {
      float4 s4 = s4r[r], e4 = e4r[r];
      float ax = (s4.x * ci) * __builtin_amdgcn_rcpf(ei + e4.x);
      float ay = (s4.y * ci) * __builtin_amdgcn_rcpf(ei + e4.y);
      float az = (s4.z * ci) * __builtin_amdgcn_rcpf(ei + e4.z);
      float aw = (s4.w * ci) * __builtin_amdgcn_rcpf(ei + e4.w);
      unsigned h01 = cvtpk(ax, ay), h23 = cvtpk(az, aw);
      float hx = bitf(h01 << 16), hy = bitf(h01 & 0xffff0000u);
      float hz = bitf(h23 << 16), hw = bitf(h23 & 0xffff0000u);
      unsigned l01 = cvtpk(ax - hx, ay - hy), l23 = cvtpk(az - hz, aw - hw);
      if ((r & 1) == 0) {
        aHc[r >> 1].x = h01; aHc[r >> 1].y = h23;
        aLc[r >> 1].x = l01; aLc[r >> 1].y = l23;
      } else {
        aHc[r >> 1].z = h01; aHc[r >> 1].w = h23;
        aLc[r >> 1].z = l01; aLc[r >> 1].w = l23;
      }
    }
  };
  auto stageB = [&](int buf, int kb) {
    unsigned short* base = (wave < 2) ? &Bh[buf][0] : &Bl[buf][0];
#pragma unroll
    for (int i = 0; i < 8; i++)
      __builtin_amdgcn_global_load_lds((glb_u32*)(gB + gbase[i] + kb),
                                       (lds_u32*)(base + ldsq[i]), 16, 0, 0);
  };

  loadA(0);
  gateA();
  stageB(0, 0);
  constexpr int NT = SQ / 32;
  for (int t = 0; t < NT; t++) {
    int cur = t & 1;
    __builtin_amdgcn_s_barrier();
#pragma unroll
    for (int cc = 0; cc < 2; cc++) {
      *(uint4*)&Ah[offA[cc]] = aHc[cc];
      *(uint4*)&Al[offA[cc]] = aLc[cc];
    }
    int kn = (t + 1 < NT) ? (t + 1) * 32 : t * 32;
    loadA(kn);
    stageB(cur ^ 1, kn);
    asm volatile("s_waitcnt lgkmcnt(0)" ::: "memory");
    asm volatile("s_waitcnt vmcnt(16)" ::: "memory");
    __builtin_amdgcn_s_barrier();
    __builtin_amdgcn_sched_barrier(0);
    gateA();
    bfrag ah[4], al_[4];
#pragma unroll
    for (int mf = 0; mf < 4; mf++) {
      ah[mf] = *(const bfrag*)&Ah[aoff[mf]];
      al_[mf] = *(const bfrag*)&Al[aoff[mf]];
    }
#pragma unroll
    for (int nf = 0; nf < 8; nf++) {
      bfrag bh = *(const bfrag*)&Bh[cur][boff[nf]];
      bfrag bl = *(const bfrag*)&Bl[cur][boff[nf]];
#pragma unroll
      for (int mf = 0; mf < 4; mf++) {
        acc[mf][nf] = __builtin_amdgcn_mfma_f32_16x16x32_bf16(al_[mf], bh, acc[mf][nf], 0, 0, 0);
        acc[mf][nf] = __builtin_amdgcn_mfma_f32_16x16x32_bf16(ah[mf], bl, acc[mf][nf], 0, 0, 0);
        acc[mf][nf] = __builtin_amdgcn_mfma_f32_16x16x32_bf16(ah[mf], bh, acc[mf][nf], 0, 0, 0);
      }
    }
    __builtin_amdgcn_sched_barrier(0);
  }
#pragma unroll
  for (int mf = 0; mf < 4; mf++) {
#pragma unroll
    for (int nf = 0; nf < 8; nf++) {
      int col = n0 + wc * 128 + nf * 16 + l16;
#pragma unroll
      for (int r = 0; r < 4; r++) {
        int row = m0 + wr * 64 + mf * 16 + quad * 4 + r;
        float o = acc[mf][nf][r];
        unsigned short hh = f2bf(o);
        Chb[(long long)row * (NH * EE) + col] = hh;
        Clb[(long long)row * (NH * EE) + col] = f2bf(o - bf2f(hh));
      }
    }
  }
}

// ================= bf16x3 MFMA NT-GEMM, pre-split operands, DMA-staged, WIDE =================
template <int ACT, int OUTM>
__global__ __launch_bounds__(256) void gemm_bf3w(
    const unsigned short* __restrict__ Ah_g, const unsigned short* __restrict__ Al_g, int lda,
    const unsigned short* __restrict__ Bh_g, const unsigned short* __restrict__ Bl_g, int ldb,
    const float* __restrict__ bias, const float* __restrict__ Res,
    float* __restrict__ C, unsigned short* __restrict__ Ch, unsigned short* __restrict__ Cl,
    int ldc, int K) {
  __shared__ __align__(16) unsigned short lds[3 * 12288];  // 3 bufs x 24 KB
  int gx = gridDim.x;
  int nwg = gx * (int)gridDim.y;
  int lin = blockIdx.y * gx + blockIdx.x;
  int cpx = nwg >> 3;
  int tl = (lin & 7) * cpx + (lin >> 3);
  int bx = tl % gx, by = tl / gx;
  int m0 = by * 128, n0 = bx * 64;
  int tid = threadIdx.x, wave = tid >> 6, lane = tid & 63;
  int quad = lane >> 4, l16 = lane & 15;

  const unsigned short* gptr[6];
  int ldsoff[6];
#pragma unroll
  for (int i = 0; i < 6; i++) {
    int d = wave * 6 + i;
    const unsigned short* src;
    int rowbase, ld, tb, qt;
    if (d < 8)       { src = Ah_g; rowbase = m0; ld = lda; tb = 0;     qt = d; }
    else if (d < 16) { src = Al_g; rowbase = m0; ld = lda; tb = 4096;  qt = d - 8; }
    else if (d < 20) { src = Bh_g; rowbase = n0; ld = ldb; tb = 8192;  qt = d - 16; }
    else             { src = Bl_g; rowbase = n0; ld = ldb; tb = 10240; qt = d - 20; }
    int row = qt * 16 + (lane >> 2);
    int cG = (lane & 3) ^ ((row >> 1) & 3);
    gptr[i] = src + (long long)(rowbase + row) * ld + cG * 8;
    ldsoff[i] = tb + qt * 512;
  }

  auto stage = [&](int buf, int kb) {
#pragma unroll
    for (int i = 0; i < 6; i++)
      __builtin_amdgcn_global_load_lds((glb_u32*)(gptr[i] + kb),
                                       (lds_u32*)&lds[buf * 12288 + ldsoff[i]], 16, 0, 0);
  };

  int aoff[4], boff[2];
#pragma unroll
  for (int mf = 0; mf < 4; mf++) {
    int r = (wave >> 1) * 64 + mf * 16 + l16;
    aoff[mf] = r * 32 + ((quad ^ ((r >> 1) & 3)) * 8);
  }
#pragma unroll
  for (int nf = 0; nf < 2; nf++) {
    int r = (wave & 1) * 32 + nf * 16 + l16;
    boff[nf] = r * 32 + ((quad ^ ((r >> 1) & 3)) * 8);
  }

  f32x4 acc[4][2];
#pragma unroll
  for (int mf = 0; mf < 4; mf++)
#pragma unroll
    for (int nf = 0; nf < 2; nf++) acc[mf][nf] = (f32x4)(0.f);

  int NT = K >> 5;
  stage(0, 0);
  stage(1, 32);
  int cur = 0;
  for (int t = 0; t < NT; t++) {
    int nb = cur + 2; if (nb >= 3) nb -= 3;
    int kf = (t + 2 < NT) ? (t + 2) * 32 : (NT - 1) * 32;  // tail: dummy (unread buffer)
    stage(nb, kf);
    asm volatile("s_waitcnt vmcnt(12)" ::: "memory");
    __builtin_amdgcn_s_barrier();
    __builtin_amdgcn_sched_barrier(0);
    const unsigned short* L = &lds[cur * 12288];
    bfrag bh[2], bl[2];
#pragma unroll
    for (int nf = 0; nf < 2; nf++) {
      bh[nf] = *(const bfrag*)&L[8192 + boff[nf]];
      bl[nf] = *(const bfrag*)&L[10240 + boff[nf]];
    }
#pragma unroll
    for (int mf = 0; mf < 4; mf++) {
      bfrag ah = *(const bfrag*)&L[aoff[mf]];
      bfrag al = *(const bfrag*)&L[4096 + aoff[mf]];
#pragma unroll
      for (int nf = 0; nf < 2; nf++) {
        acc[mf][nf] = __builtin_amdgcn_mfma_f32_16x16x32_bf16(al, bh[nf], acc[mf][nf], 0, 0, 0);
        acc[mf][nf] = __builtin_amdgcn_mfma_f32_16x16x32_bf16(ah, bl[nf], acc[mf][nf], 0, 0, 0);
        acc[mf][nf] = __builtin_amdgcn_mfma_f32_16x16x32_bf16(ah, bh[nf], acc[mf][nf], 0, 0, 0);
      }
    }
    __builtin_amdgcn_sched_barrier(0);
    __builtin_amdgcn_s_barrier();
    cur++; if (cur >= 3) cur -= 3;
  }

  // epilogue: C/D layout row = quad*4 + r, col = l16
#pragma unroll
  for (int mf = 0; mf < 4; mf++) {
#pragma unroll
    for (int nf = 0; nf < 2; nf++) {
      int col = n0 + (wave & 1) * 32 + nf * 16 + l16;
      float bi = bias ? bias[col] : 0.f;
#pragma unroll
      for (int r = 0; r < 4; r++) {
        int row = m0 + (wave >> 1) * 64 + mf * 16 + quad * 4 + r;
        float o = acc[mf][nf][r] + bi;
        if (ACT == 1) o = gelu_exact(o);
        if (OUTM == 0) {
          if (Res) o = o + Res[(long long)row * ldc + col];
          C[(long long)row * ldc + col] = o;
        } else {
          unsigned short hh = f2bf(o);
          Ch[(long long)row * ldc + col] = hh;
          Cl[(long long)row * ldc + col] = f2bf(o - bf2f(hh));
        }
      }
    }
  }
}

extern "C" void kernel_launch(void* const* d_in, const int* in_sizes, int n_in,
                              void* d_out, int out_size, void* d_ws, size_t ws_size,
                              hipStream_t stream) {
  const float* query     = (const float*)d_in[0];
  const float* ln1_g     = (const float*)d_in[1];
  const float* ln1_b     = (const float*)d_in[2];
  const float* in_proj_w = (const float*)d_in[3];
  const float* in_proj_b = (const float*)d_in[4];
  const float* out_w     = (const float*)d_in[5];
  const float* out_b     = (const float*)d_in[6];
  const float* conv_w    = (const float*)d_in[7];
  const float* conv_b    = (const float*)d_in[8];
  const float* ln2_g     = (const float*)d_in[9];
  const float* ln2_b     = (const float*)d_in[10];
  const float* mlp_w1    = (const float*)d_in[11];
  const float* mlp_b1    = (const float*)d_in[12];
  const float* mlp_w2    = (const float*)d_in[13];
  const float* mlp_b2    = (const float*)d_in[14];
  float* out = (float*)d_out;
  char* ws = (char*)d_ws;

  // Round-4/6 proven workspace layout (peak 112.25 MiB). Lifetime-disjoint reuse:
  float* nq     = (float*)(ws + 0);                      // [0,8)   dead after step 3
  float* qkv    = (float*)(ws + (8ull << 20));           // [8,32)  dead after step 4
  float* dist   = (float*)(ws + (32ull << 20));          // 128 KiB
  float* invrs  = (float*)(ws + (32ull << 20) + 131072); // 128 KiB
  float* scores = (float*)(ws + (32ull << 20) + 262144); // [32.25,48.25) dead after step 6
  unsigned short* VhT = (unsigned short*)(ws + 0);             // over dead nq, 4 MiB (3b-6)
  unsigned short* VlT = (unsigned short*)(ws + (4ull << 20));  // 4 MiB
  // ctx pre-split: [48.25,112.25)
  unsigned short* ctxh = (unsigned short*)(ws + (48ull << 20) + 262144);  // 32 MiB
  unsigned short* ctxl = (unsigned short*)(ws + (80ull << 20) + 262144);  // 32 MiB
  // weight splits in dead scores region (written 6b, live to 10):
  unsigned short* out_wh = (unsigned short*)(ws + (32ull << 20) + 262144);  // 4 MiB
  unsigned short* out_wl = out_wh + 2097152;                                // 4 MiB
  unsigned short* w1h    = out_wl + 2097152;                                // 2 MiB
  unsigned short* w1l    = w1h + 1048576;                                   // 2 MiB
  unsigned short* w2h    = w1l + 1048576;                                   // 2 MiB
  unsigned short* w2l    = w2h + 1048576;                                   // 2 MiB (ends at 48.25)
  // LN2 split over dead ctxh (after step 7):
  unsigned short* ln2h = (unsigned short*)(ws + (48ull << 20) + 262144);  // 4 MiB
  unsigned short* ln2l = ln2h + 2097152;                                  // 4 MiB
  // MLP hidden split over dead nq+qkv (after step 6):
  unsigned short* hbufh = (unsigned short*)(ws + 0);        // 16 MiB
  unsigned short* hbufl = hbufh + 8388608;                  // 16 MiB (ends at 32)
  // Edist (128 KiB) lives in d_out scratch: written step 2, read step 6;
  // step 7 (stream-ordered after 6) overwrites out with the real output.
  float* Edist = (float*)d_out;

  // 1. LN1 (frozen)
  ln_np<<<dim3(NB * SQ), 64, 0, stream>>>(query, ln1_g, ln1_b, nq);
  // 2. distances (frozen) + E = __expf(dist) for ctx gate
  dist_np<<<dim3(NB * NH, 4), 256, 0, stream>>>(nq, conv_w, conv_b, dist, Edist);
  // 3. qkv (frozen chain, 64x192 tile, balanced 512 blocks)  M=4096 N=1536 K=512
  gemm_nt4<0, 384><<<dim3(8, 64, 1), 256, 0, stream>>>(nq, EE, 0, in_proj_w, EE, 0,
                                                       in_proj_b, nullptr, qkv, 3 * EE, 0, EE, 1.f);
  // 3b. V transpose + bf16 hi/lo split
  vsplit_t<<<dim3(16, 8, NB), 256, 0, stream>>>(qkv, VhT, VlT);
  // 4. scores (frozen chain + true division, 128x128 tile — r9 proven)  M=N=1024 K=512
  gemm_nt2<2, 384><<<dim3(8, 8, NB), 256, 0, stream>>>(
      qkv, 3 * EE, (long long)SQ * 3 * EE, qkv + EE, 3 * EE, (long long)SQ * 3 * EE,
      nullptr, nullptr, scores, SQ, (long long)SQ * SQ, EE, sqrtf(512.0f));
  // 5. gated row sums (frozen, fp64 exp)
  rowsum_np<<<dim3(SQ, NB * NH), 64, 0, stream>>>(scores, dist, invrs);
  // 6. ctx via bf16x3 MFMA, 128x256 tile, B-DMA + XOR LDS  M=1024 N=512 K=1024
  ctx_bf3<<<dim3(2, 8, NB * NH), 256, 0, stream>>>(scores, Edist, invrs, VhT, VlT, ctxh, ctxl);
  // 6b. weight splits (scores region is dead now)
  wsplit<<<dim3(2048), 256, 0, stream>>>(out_w, out_wh, out_wl, 524288);
  wsplit<<<dim3(1024), 256, 0, stream>>>(mlp_w1, w1h, w1l, 262144);
  wsplit<<<dim3(1024), 256, 0, stream>>>(mlp_w2, w2h, w2l, 262144);
  // 7. attn_out + residual (wide DMA bf16x3)  M=4096 N=512 K=4096
  gemm_bf3w<0, 0><<<dim3(8, 32), 256, 0, stream>>>(ctxh, ctxl, NH * EE, out_wh, out_wl, NH * EE,
                                                   out_b, query, out, nullptr, nullptr,
                                                   EE, NH * EE);
  // 8. LN2, split output
  ln_np_s<<<dim3(NB * SQ), 64, 0, stream>>>(out, ln2_g, ln2_b, ln2h, ln2l);
  // 9. MLP1 + gelu, split output (wide DMA bf16x3)  M=4096 N=2048 K=512
  gemm_bf3w<1, 1><<<dim3(32, 32), 256, 0, stream>>>(ln2h, ln2l, EE, w1h, w1l, EE,
                                                    mlp_b1, nullptr, nullptr, hbufh, hbufl,
                                                    4 * EE, EE);
  // 10. MLP2 + residual (wide DMA bf16x3)  M=4096 N=512 K=2048
  gemm_bf3w<0, 0><<<dim3(8, 32), 256, 0, stream>>>(hbufh, hbufl, 4 * EE, w2h, w2l, 4 * EE,
                                                   mlp_b2, out, out, nullptr, nullptr,
                                                   EE, 4 * EE);
}